// Round 9
// baseline (96.839 us; speedup 1.0000x reference)
//
#include <hip/hip_runtime.h>
#include <hip/hip_bf16.h>

typedef __bf16 bf16x8 __attribute__((ext_vector_type(8)));
typedef __bf16 bf16x4 __attribute__((ext_vector_type(4)));
typedef float  floatx4 __attribute__((ext_vector_type(4)));

#define SD 4096
#define DH 64
#define NB 4

__device__ __forceinline__ float exp2fast(float x) { return __builtin_amdgcn_exp2f(x); }

__device__ __forceinline__ unsigned pack_bf16_2(float a, float b) {
    union { __bf16 h[2]; unsigned u; } cvt;
    cvt.h[0] = (__bf16)a; cvt.h[1] = (__bf16)b;
    return cvt.u;
}

// LDS-visibility barrier WITHOUT vmcnt(0) drain: in-flight global prefetch
// loads stay outstanding across the barrier.
__device__ __forceinline__ void block_sync_lds() {
    asm volatile("s_waitcnt lgkmcnt(0)\n\ts_barrier" ::: "memory");
}

// Pre-pass: K fp32 -> bf16 (natural layout). V fp32 -> bf16 transposed
// VT[b][d][col], columns within each 64-key tile PERMUTED so P^T exits the
// QK^T MFMA already in B-operand order:
//   col -> key = 16*(2*(col>>5) + ((col>>2)&1)) + 4*((col>>3)&3) + (col&3)
__global__ __launch_bounds__(256) void prep_kernel(const float* __restrict__ k,
                                                   const float* __restrict__ v,
                                                   __bf16* __restrict__ kb,
                                                   __bf16* __restrict__ vt) {
    __shared__ __bf16 tile[16][80];   // [dloc][key]
    const int bid = blockIdx.x;
    const int tid = threadIdx.x;
    {
        long off = (long)bid * 1024 + tid * 4;
        float4 f = *(const float4*)(k + off);
        bf16x4 o; o[0]=(__bf16)f.x; o[1]=(__bf16)f.y; o[2]=(__bf16)f.z; o[3]=(__bf16)f.w;
        *(bf16x4*)(kb + off) = o;
    }
    const int b = bid >> 8, kt = (bid >> 2) & 63, dq = bid & 3;
    {
        int key = tid >> 2, ds = (tid & 3) * 4;
        float4 f = *(const float4*)(v + ((long)b * SD + kt * 64 + key) * DH + dq * 16 + ds);
        tile[ds+0][key] = (__bf16)f.x;
        tile[ds+1][key] = (__bf16)f.y;
        tile[ds+2][key] = (__bf16)f.z;
        tile[ds+3][key] = (__bf16)f.w;
    }
    __syncthreads();
    {
        int dloc = tid >> 4, cs = (tid & 15) * 4;
        bf16x4 o;
#pragma unroll
        for (int i = 0; i < 4; ++i) {
            int col = cs + i;
            int key = ((col >> 5) * 2 + ((col >> 2) & 1)) * 16
                    + ((col >> 3) & 3) * 4 + (col & 3);
            o[i] = tile[dloc][key];
        }
        *(bf16x4*)(vt + ((long)b * DH + dq * 16 + dloc) * SD + kt * 64 + cs) = o;
    }
}

// Flash attention, pipelined LDS staging, 32 q-rows per wave (two 16-q MFMA
// fragments share every K/V LDS read -> LDS traffic per MFMA halved vs R7).
// Block = 256 thr / 4 waves = 128-row Q tile; phases {T, 31-T} (uniform 66
// k-tiles); keys split 8-way across blocks (qr) -> 512 uniform blocks.
// Partials (O^T, l) to ws; combine kernel merges the 8 key-eighths.
__global__ __launch_bounds__(256, 2) void fa_kernel(const float* __restrict__ q,
                                                    const __bf16* __restrict__ kb,
                                                    const __bf16* __restrict__ vt,
                                                    float* __restrict__ opart,
                                                    float* __restrict__ lpart) {
    __shared__ __bf16 smem[2][8192];   // [buf][ K: 0..4095 | V: 4096..8191 ]

    const int tid  = threadIdx.x;
    const int wave = tid >> 6;
    const int lane = tid & 63;
    const int c    = lane & 15;
    const int quad = lane >> 4;
    const int bid   = blockIdx.x;
    const int batch = bid & 3;
    const int pr    = (bid >> 2) & 15;   // pair index 0..15
    const int qr    = bid >> 6;          // key-eighth 0..7
    const float sc = 0.125f * 1.4426950408889634f;

    const long offB   = (long)batch * SD * DH;
    const long vtoffB = (long)batch * DH * SD;

    // staging: thread owns chunks {tid, tid+256} of K and of V (16B each)
    const int gk0 = tid, gk1 = tid + 256;
    auto swz = [](int g) { int row = g >> 3, ch = g & 7; return row * 64 + ((ch ^ (row & 7)) << 3); };
    const int wk0 = swz(gk0), wk1 = swz(gk1);
    const int wv0 = 4096 + wk0, wv1 = 4096 + wk1;
    const int sw   = c & 7;
    const int off0 = ((quad ^ sw) << 3);
    const int off1 = (((quad + 4) ^ sw) << 3);
    const int rowc = c * 64;

#pragma unroll 1
    for (int ph = 0; ph < 2; ++ph) {
        const int T = ph ? 31 - pr : pr;
        const int myq = T * 128 + wave * 32;   // this wave's 32 q rows

        // Q fragments (B operand) for both 16-q halves, pre-scaled
        bf16x8 qf0A, qf1A, qf0B, qf1B;
#pragma unroll
        for (int h = 0; h < 2; ++h) {
            const float* qp = q + offB + (long)(myq + h*16 + c) * DH + quad * 8;
            float4 f0 = *(const float4*)(qp);
            float4 f1 = *(const float4*)(qp + 4);
            float4 f2 = *(const float4*)(qp + 32);
            float4 f3 = *(const float4*)(qp + 36);
            bf16x8 t0, t1;
            t0[0]=(__bf16)(f0.x*sc); t0[1]=(__bf16)(f0.y*sc); t0[2]=(__bf16)(f0.z*sc); t0[3]=(__bf16)(f0.w*sc);
            t0[4]=(__bf16)(f1.x*sc); t0[5]=(__bf16)(f1.y*sc); t0[6]=(__bf16)(f1.z*sc); t0[7]=(__bf16)(f1.w*sc);
            t1[0]=(__bf16)(f2.x*sc); t1[1]=(__bf16)(f2.y*sc); t1[2]=(__bf16)(f2.z*sc); t1[3]=(__bf16)(f2.w*sc);
            t1[4]=(__bf16)(f3.x*sc); t1[5]=(__bf16)(f3.y*sc); t1[6]=(__bf16)(f3.z*sc); t1[7]=(__bf16)(f3.w*sc);
            if (h == 0) { qf0A = t0; qf1A = t1; } else { qf0B = t0; qf1B = t1; }
        }

        floatx4 oA0 = {0.f,0.f,0.f,0.f}, oA1 = oA0, oA2 = oA0, oA3 = oA0;
        floatx4 oB0 = oA0, oB1 = oA0, oB2 = oA0, oB3 = oA0;
        float lA = 0.0f, lB = 0.0f;

        const int kmax = 2 * T + 1;                              // last k-tile
        const int n = (kmax >= qr) ? ((kmax - qr) >> 3) + 1 : 0; // block-uniform

        bf16x8 sk0, sk1, sv0, sv1;
        auto stage = [&](int kt, bf16x8& a, bf16x8& b, bf16x8& cc, bf16x8& dd) {
            const __bf16* kg = kb + offB + kt * 4096;
            a  = *(const bf16x8*)(kg + gk0 * 8);
            b  = *(const bf16x8*)(kg + gk1 * 8);
            const __bf16* vg = vt + vtoffB + kt * 64;
            cc = *(const bf16x8*)(vg + (long)(gk0 >> 3) * SD + (gk0 & 7) * 8);
            dd = *(const bf16x8*)(vg + (long)(gk1 >> 3) * SD + (gk1 & 7) * 8);
        };

        if (n > 0) stage(qr, sk0, sk1, sv0, sv1);
        block_sync_lds();   // prior phase's LDS reads complete before re-staging

#pragma unroll 1
        for (int j = 0; j < n; ++j) {
            const int kt = qr + 8 * j;
            bf16x8 nk0, nk1, nv0, nv1;
            if (j + 1 < n) stage(kt + 8, nk0, nk1, nv0, nv1);
            __bf16* buf = smem[j & 1];
            *(bf16x8*)(buf + wk0) = sk0;
            *(bf16x8*)(buf + wk1) = sk1;
            *(bf16x8*)(buf + wv0) = sv0;
            *(bf16x8*)(buf + wv1) = sv1;
            sk0 = nk0; sk1 = nk1; sv0 = nv0; sv1 = nv1;
            block_sync_lds();

            const int kbase = kt * 64;
            if (kbase > myq + 31) continue;   // fully-masked for this wave (uniform)

            const __bf16* kbuf = buf;
            const __bf16* vbuf = buf + 4096;
            floatx4 saA[4], saB[4];
#pragma unroll
            for (int t = 0; t < 4; ++t) {
                bf16x8 ka  = *(const bf16x8*)(kbuf + t * 1024 + rowc + off0);
                bf16x8 kb2 = *(const bf16x8*)(kbuf + t * 1024 + rowc + off1);
                floatx4 a = {0.f,0.f,0.f,0.f}, b = a;
                a = __builtin_amdgcn_mfma_f32_16x16x32_bf16(ka,  qf0A, a, 0, 0, 0);
                a = __builtin_amdgcn_mfma_f32_16x16x32_bf16(kb2, qf1A, a, 0, 0, 0);
                b = __builtin_amdgcn_mfma_f32_16x16x32_bf16(ka,  qf0B, b, 0, 0, 0);
                b = __builtin_amdgcn_mfma_f32_16x16x32_bf16(kb2, qf1B, b, 0, 0, 0);
                saA[t] = a; saB[t] = b;
            }
            float peA[16], peB[16];
            if (kbase + 63 > myq) {   // diagonal region: apply causal mask
                const int qrA = myq + c, qrB = myq + 16 + c;
#pragma unroll
                for (int t = 0; t < 4; ++t)
#pragma unroll
                    for (int r = 0; r < 4; ++r) {
                        int key = kbase + t*16 + quad*4 + r;
                        peA[t*4+r] = (key <= qrA) ? exp2fast(saA[t][r]) : 0.0f;
                        peB[t*4+r] = (key <= qrB) ? exp2fast(saB[t][r]) : 0.0f;
                    }
            } else {
#pragma unroll
                for (int t = 0; t < 4; ++t)
#pragma unroll
                    for (int r = 0; r < 4; ++r) {
                        peA[t*4+r] = exp2fast(saA[t][r]);
                        peB[t*4+r] = exp2fast(saB[t][r]);
                    }
            }
            {
                float s8[8], s4v[4];
#pragma unroll
                for (int i = 0; i < 8; ++i) s8[i] = peA[i] + peA[i+8];
#pragma unroll
                for (int i = 0; i < 4; ++i) s4v[i] = s8[i] + s8[i+4];
                lA += (s4v[0] + s4v[2]) + (s4v[1] + s4v[3]);
#pragma unroll
                for (int i = 0; i < 8; ++i) s8[i] = peB[i] + peB[i+8];
#pragma unroll
                for (int i = 0; i < 4; ++i) s4v[i] = s8[i] + s8[i+4];
                lB += (s4v[0] + s4v[2]) + (s4v[1] + s4v[3]);
            }
#pragma unroll
            for (int s = 0; s < 2; ++s) {
                union { unsigned u[4]; bf16x8 f; } bpA, bpB;
#pragma unroll
                for (int jj = 0; jj < 4; ++jj) {
                    bpA.u[jj] = pack_bf16_2(peA[8*s + 2*jj], peA[8*s + 2*jj + 1]);
                    bpB.u[jj] = pack_bf16_2(peB[8*s + 2*jj], peB[8*s + 2*jj + 1]);
                }
                const int offs = s ? off1 : off0;
                bf16x8 v0 = *(const bf16x8*)(vbuf + 0*1024 + rowc + offs);
                bf16x8 v1 = *(const bf16x8*)(vbuf + 1*1024 + rowc + offs);
                bf16x8 v2 = *(const bf16x8*)(vbuf + 2*1024 + rowc + offs);
                bf16x8 v3 = *(const bf16x8*)(vbuf + 3*1024 + rowc + offs);
                oA0 = __builtin_amdgcn_mfma_f32_16x16x32_bf16(v0, bpA.f, oA0, 0, 0, 0);
                oA1 = __builtin_amdgcn_mfma_f32_16x16x32_bf16(v1, bpA.f, oA1, 0, 0, 0);
                oA2 = __builtin_amdgcn_mfma_f32_16x16x32_bf16(v2, bpA.f, oA2, 0, 0, 0);
                oA3 = __builtin_amdgcn_mfma_f32_16x16x32_bf16(v3, bpA.f, oA3, 0, 0, 0);
                oB0 = __builtin_amdgcn_mfma_f32_16x16x32_bf16(v0, bpB.f, oB0, 0, 0, 0);
                oB1 = __builtin_amdgcn_mfma_f32_16x16x32_bf16(v1, bpB.f, oB1, 0, 0, 0);
                oB2 = __builtin_amdgcn_mfma_f32_16x16x32_bf16(v2, bpB.f, oB2, 0, 0, 0);
                oB3 = __builtin_amdgcn_mfma_f32_16x16x32_bf16(v3, bpB.f, oB3, 0, 0, 0);
            }
        }

        lA += __shfl_xor(lA, 16); lA += __shfl_xor(lA, 32);
        lB += __shfl_xor(lB, 16); lB += __shfl_xor(lB, 32);

        // ---- partial stores (always; eighths with n==0 must write zeros) ----
        float* ob = opart + ((long)qr * NB + batch) * (long)(SD * DH) + (long)myq * DH;
        {
            floatx4 ovA[4] = {oA0, oA1, oA2, oA3};
            floatx4 ovB[4] = {oB0, oB1, oB2, oB3};
#pragma unroll
            for (int dt = 0; dt < 4; ++dt) {
                *(floatx4*)(ob + (c)      * DH + dt*16 + quad*4) = ovA[dt];
                *(floatx4*)(ob + (16 + c) * DH + dt*16 + quad*4) = ovB[dt];
            }
        }
        if (quad == 0) {
            lpart[((long)qr * NB + batch) * SD + myq + c]      = lA;
            lpart[((long)qr * NB + batch) * SD + myq + 16 + c] = lB;
        }
    }
}

// out = (sum of 8 key-eighth O partials) / (sum of 8 l partials)
__global__ __launch_bounds__(256) void combine_kernel(const float* __restrict__ opart,
                                                      const float* __restrict__ lpart,
                                                      float* __restrict__ out) {
    const long idx = (long)blockIdx.x * 256 + threadIdx.x;   // b*SD*DH + q*DH + d
    const long qq  = idx >> 6;                               // b*SD + q
    float num = 0.f, den = 0.f;
#pragma unroll
    for (int qr = 0; qr < 8; ++qr) {
        num += opart[((long)qr << 20) + idx];    // stride NB*SD*DH = 1048576
        den += lpart[((long)qr << 14) + qq];     // stride NB*SD   = 16384
    }
    out[idx] = num / den;
}

extern "C" void kernel_launch(void* const* d_in, const int* in_sizes, int n_in,
                              void* d_out, int out_size, void* d_ws, size_t ws_size,
                              hipStream_t stream) {
    const float* q = (const float*)d_in[0];
    const float* k = (const float*)d_in[1];
    const float* v = (const float*)d_in[2];
    float* out = (float*)d_out;
    __bf16* kb  = (__bf16*)d_ws;
    __bf16* vtb = kb + (size_t)NB * SD * DH;                       // +2MB
    float*  opart = (float*)((char*)d_ws + (4u << 20));            // 32MB
    float*  lpart = (float*)((char*)d_ws + (36u << 20));           // 512KB
    prep_kernel<<<dim3(1024), dim3(256), 0, stream>>>(k, v, kb, vtb);
    fa_kernel<<<dim3(512), dim3(256), 0, stream>>>(q, kb, vtb, opart, lpart);
    combine_kernel<<<dim3(4096), dim3(256), 0, stream>>>(opart, lpart, out);
}

// Round 10
// 93.355 us; speedup vs baseline: 1.0373x; 1.0373x over previous
//
#include <hip/hip_runtime.h>
#include <hip/hip_bf16.h>

typedef __bf16 bf16x8 __attribute__((ext_vector_type(8)));
typedef __bf16 bf16x4 __attribute__((ext_vector_type(4)));
typedef float  floatx4 __attribute__((ext_vector_type(4)));

#define SD 4096
#define DH 64
#define NB 4

__device__ __forceinline__ float exp2fast(float x) { return __builtin_amdgcn_exp2f(x); }

__device__ __forceinline__ unsigned pack_bf16_2(float a, float b) {
    union { __bf16 h[2]; unsigned u; } cvt;
    cvt.h[0] = (__bf16)a; cvt.h[1] = (__bf16)b;
    return cvt.u;
}

// LDS-visibility barrier WITHOUT vmcnt(0) drain: in-flight global prefetch
// loads stay outstanding across the barrier.
__device__ __forceinline__ void block_sync_lds() {
    asm volatile("s_waitcnt lgkmcnt(0)\n\ts_barrier" ::: "memory");
}

// Pre-pass (V ONLY now; K is converted inside fa staging): V fp32 -> bf16
// transposed VT[b][d][col], columns within each 64-key tile PERMUTED so P^T
// exits the QK^T MFMA already in B-operand order:
//   col -> key = 16*(2*(col>>5) + ((col>>2)&1)) + 4*((col>>3)&3) + (col&3)
__global__ __launch_bounds__(256) void prep_kernel(const float* __restrict__ v,
                                                   __bf16* __restrict__ vt) {
    __shared__ __bf16 tile[16][80];   // [dloc][key]
    const int bid = blockIdx.x;
    const int tid = threadIdx.x;
    const int b = bid >> 8, kt = (bid >> 2) & 63, dq = bid & 3;
    {
        int key = tid >> 2, ds = (tid & 3) * 4;
        float4 f = *(const float4*)(v + ((long)b * SD + kt * 64 + key) * DH + dq * 16 + ds);
        tile[ds+0][key] = (__bf16)f.x;
        tile[ds+1][key] = (__bf16)f.y;
        tile[ds+2][key] = (__bf16)f.z;
        tile[ds+3][key] = (__bf16)f.w;
    }
    __syncthreads();
    {
        int dloc = tid >> 4, cs = (tid & 15) * 4;
        bf16x4 o;
#pragma unroll
        for (int i = 0; i < 4; ++i) {
            int col = cs + i;
            int key = ((col >> 5) * 2 + ((col >> 2) & 1)) * 16
                    + ((col >> 3) & 3) * 4 + (col & 3);
            o[i] = tile[dloc][key];
        }
        *(bf16x4*)(vt + ((long)b * DH + dq * 16 + dloc) * SD + kt * 64 + cs) = o;
    }
}

// Flash attention, pipelined LDS staging, 32 q-rows per wave. K is staged
// DIRECTLY from the fp32 input (convert in-register at commit) — no K prep
// pass. Block = 256 thr / 4 waves = 128-row Q tile; phases {T, 31-T}; keys
// split 8-way across blocks (qr) -> 512 uniform blocks. O^T partials stored
// as bf16 (halves combine traffic); l partials fp32.
__global__ __launch_bounds__(256, 2) void fa_kernel(const float* __restrict__ q,
                                                    const float* __restrict__ kq,
                                                    const __bf16* __restrict__ vt,
                                                    __bf16* __restrict__ opart,
                                                    float* __restrict__ lpart) {
    __shared__ __bf16 smem[2][8192];   // [buf][ K: 0..4095 | V: 4096..8191 ]

    const int tid  = threadIdx.x;
    const int wave = tid >> 6;
    const int lane = tid & 63;
    const int c    = lane & 15;
    const int quad = lane >> 4;
    const int bid   = blockIdx.x;
    const int batch = bid & 3;
    const int pr    = (bid >> 2) & 15;   // pair index 0..15
    const int qr    = bid >> 6;          // key-eighth 0..7
    const float sc = 0.125f * 1.4426950408889634f;

    const long offB   = (long)batch * SD * DH;
    const long vtoffB = (long)batch * DH * SD;

    // K staging: thread owns row krow, d columns kdc..kdc+15 (two 8-chunks)
    const int krow = tid >> 2, kdc = (tid & 3) * 16;
    auto swz = [](int g) { int row = g >> 3, ch = g & 7; return row * 64 + ((ch ^ (row & 7)) << 3); };
    const int wkA = swz(krow * 8 + (tid & 3) * 2);
    const int wkB = swz(krow * 8 + (tid & 3) * 2 + 1);
    // V staging: thread owns chunks {tid, tid+256} of VT tile
    const int gk0 = tid, gk1 = tid + 256;
    const int wv0 = 4096 + swz(gk0), wv1 = 4096 + swz(gk1);
    const int sw   = c & 7;
    const int off0 = ((quad ^ sw) << 3);
    const int off1 = (((quad + 4) ^ sw) << 3);
    const int rowc = c * 64;

#pragma unroll 1
    for (int ph = 0; ph < 2; ++ph) {
        const int T = ph ? 31 - pr : pr;
        const int myq = T * 128 + wave * 32;   // this wave's 32 q rows

        // Q fragments (B operand) for both 16-q halves, pre-scaled
        bf16x8 qf0A, qf1A, qf0B, qf1B;
#pragma unroll
        for (int h = 0; h < 2; ++h) {
            const float* qp = q + offB + (long)(myq + h*16 + c) * DH + quad * 8;
            float4 f0 = *(const float4*)(qp);
            float4 f1 = *(const float4*)(qp + 4);
            float4 f2 = *(const float4*)(qp + 32);
            float4 f3 = *(const float4*)(qp + 36);
            bf16x8 t0, t1;
            t0[0]=(__bf16)(f0.x*sc); t0[1]=(__bf16)(f0.y*sc); t0[2]=(__bf16)(f0.z*sc); t0[3]=(__bf16)(f0.w*sc);
            t0[4]=(__bf16)(f1.x*sc); t0[5]=(__bf16)(f1.y*sc); t0[6]=(__bf16)(f1.z*sc); t0[7]=(__bf16)(f1.w*sc);
            t1[0]=(__bf16)(f2.x*sc); t1[1]=(__bf16)(f2.y*sc); t1[2]=(__bf16)(f2.z*sc); t1[3]=(__bf16)(f2.w*sc);
            t1[4]=(__bf16)(f3.x*sc); t1[5]=(__bf16)(f3.y*sc); t1[6]=(__bf16)(f3.z*sc); t1[7]=(__bf16)(f3.w*sc);
            if (h == 0) { qf0A = t0; qf1A = t1; } else { qf0B = t0; qf1B = t1; }
        }

        floatx4 oA0 = {0.f,0.f,0.f,0.f}, oA1 = oA0, oA2 = oA0, oA3 = oA0;
        floatx4 oB0 = oA0, oB1 = oA0, oB2 = oA0, oB3 = oA0;
        float lA = 0.0f, lB = 0.0f;

        const int kmax = 2 * T + 1;                              // last k-tile
        const int n = (kmax >= qr) ? ((kmax - qr) >> 3) + 1 : 0; // block-uniform

        float4 fk0, fk1, fk2, fk3;      // staged K (fp32, converted at commit)
        bf16x8 sv0, sv1;                // staged V (bf16)
        auto stage = [&](int kt, float4& a0, float4& a1, float4& a2, float4& a3,
                         bf16x8& v0, bf16x8& v1) {
            const float* kg = kq + offB + (long)(kt * 64 + krow) * DH + kdc;
            a0 = *(const float4*)(kg);
            a1 = *(const float4*)(kg + 4);
            a2 = *(const float4*)(kg + 8);
            a3 = *(const float4*)(kg + 12);
            const __bf16* vg = vt + vtoffB + kt * 64;
            v0 = *(const bf16x8*)(vg + (long)(gk0 >> 3) * SD + (gk0 & 7) * 8);
            v1 = *(const bf16x8*)(vg + (long)(gk1 >> 3) * SD + (gk1 & 7) * 8);
        };

        if (n > 0) stage(qr, fk0, fk1, fk2, fk3, sv0, sv1);
        block_sync_lds();   // prior phase's LDS reads complete before re-staging

#pragma unroll 1
        for (int j = 0; j < n; ++j) {
            const int kt = qr + 8 * j;
            float4 nk0, nk1, nk2, nk3; bf16x8 nv0, nv1;
            if (j + 1 < n) stage(kt + 8, nk0, nk1, nk2, nk3, nv0, nv1);
            // commit current tile: convert K fp32->bf16, write K+V to LDS
            __bf16* buf = smem[j & 1];
            {
                bf16x8 cA, cB;
                cA[0]=(__bf16)fk0.x; cA[1]=(__bf16)fk0.y; cA[2]=(__bf16)fk0.z; cA[3]=(__bf16)fk0.w;
                cA[4]=(__bf16)fk1.x; cA[5]=(__bf16)fk1.y; cA[6]=(__bf16)fk1.z; cA[7]=(__bf16)fk1.w;
                cB[0]=(__bf16)fk2.x; cB[1]=(__bf16)fk2.y; cB[2]=(__bf16)fk2.z; cB[3]=(__bf16)fk2.w;
                cB[4]=(__bf16)fk3.x; cB[5]=(__bf16)fk3.y; cB[6]=(__bf16)fk3.z; cB[7]=(__bf16)fk3.w;
                *(bf16x8*)(buf + wkA) = cA;
                *(bf16x8*)(buf + wkB) = cB;
                *(bf16x8*)(buf + wv0) = sv0;
                *(bf16x8*)(buf + wv1) = sv1;
            }
            fk0 = nk0; fk1 = nk1; fk2 = nk2; fk3 = nk3; sv0 = nv0; sv1 = nv1;
            block_sync_lds();

            const int kbase = kt * 64;
            if (kbase > myq + 31) continue;   // fully-masked for this wave

            const __bf16* kbuf = buf;
            const __bf16* vbuf = buf + 4096;
            floatx4 saA[4], saB[4];
#pragma unroll
            for (int t = 0; t < 4; ++t) {
                bf16x8 ka  = *(const bf16x8*)(kbuf + t * 1024 + rowc + off0);
                bf16x8 kb2 = *(const bf16x8*)(kbuf + t * 1024 + rowc + off1);
                floatx4 a = {0.f,0.f,0.f,0.f}, b = a;
                a = __builtin_amdgcn_mfma_f32_16x16x32_bf16(ka,  qf0A, a, 0, 0, 0);
                a = __builtin_amdgcn_mfma_f32_16x16x32_bf16(kb2, qf1A, a, 0, 0, 0);
                b = __builtin_amdgcn_mfma_f32_16x16x32_bf16(ka,  qf0B, b, 0, 0, 0);
                b = __builtin_amdgcn_mfma_f32_16x16x32_bf16(kb2, qf1B, b, 0, 0, 0);
                saA[t] = a; saB[t] = b;
            }
            float peA[16], peB[16];
            if (kbase + 63 > myq) {   // diagonal region: apply causal mask
                const int qrA = myq + c, qrB = myq + 16 + c;
#pragma unroll
                for (int t = 0; t < 4; ++t)
#pragma unroll
                    for (int r = 0; r < 4; ++r) {
                        int key = kbase + t*16 + quad*4 + r;
                        peA[t*4+r] = (key <= qrA) ? exp2fast(saA[t][r]) : 0.0f;
                        peB[t*4+r] = (key <= qrB) ? exp2fast(saB[t][r]) : 0.0f;
                    }
            } else {
#pragma unroll
                for (int t = 0; t < 4; ++t)
#pragma unroll
                    for (int r = 0; r < 4; ++r) {
                        peA[t*4+r] = exp2fast(saA[t][r]);
                        peB[t*4+r] = exp2fast(saB[t][r]);
                    }
            }
            {
                float s8[8], s4v[4];
#pragma unroll
                for (int i = 0; i < 8; ++i) s8[i] = peA[i] + peA[i+8];
#pragma unroll
                for (int i = 0; i < 4; ++i) s4v[i] = s8[i] + s8[i+4];
                lA += (s4v[0] + s4v[2]) + (s4v[1] + s4v[3]);
#pragma unroll
                for (int i = 0; i < 8; ++i) s8[i] = peB[i] + peB[i+8];
#pragma unroll
                for (int i = 0; i < 4; ++i) s4v[i] = s8[i] + s8[i+4];
                lB += (s4v[0] + s4v[2]) + (s4v[1] + s4v[3]);
            }
#pragma unroll
            for (int s = 0; s < 2; ++s) {
                union { unsigned u[4]; bf16x8 f; } bpA, bpB;
#pragma unroll
                for (int jj = 0; jj < 4; ++jj) {
                    bpA.u[jj] = pack_bf16_2(peA[8*s + 2*jj], peA[8*s + 2*jj + 1]);
                    bpB.u[jj] = pack_bf16_2(peB[8*s + 2*jj], peB[8*s + 2*jj + 1]);
                }
                const int offs = s ? off1 : off0;
                bf16x8 v0 = *(const bf16x8*)(vbuf + 0*1024 + rowc + offs);
                bf16x8 v1 = *(const bf16x8*)(vbuf + 1*1024 + rowc + offs);
                bf16x8 v2 = *(const bf16x8*)(vbuf + 2*1024 + rowc + offs);
                bf16x8 v3 = *(const bf16x8*)(vbuf + 3*1024 + rowc + offs);
                oA0 = __builtin_amdgcn_mfma_f32_16x16x32_bf16(v0, bpA.f, oA0, 0, 0, 0);
                oA1 = __builtin_amdgcn_mfma_f32_16x16x32_bf16(v1, bpA.f, oA1, 0, 0, 0);
                oA2 = __builtin_amdgcn_mfma_f32_16x16x32_bf16(v2, bpA.f, oA2, 0, 0, 0);
                oA3 = __builtin_amdgcn_mfma_f32_16x16x32_bf16(v3, bpA.f, oA3, 0, 0, 0);
                oB0 = __builtin_amdgcn_mfma_f32_16x16x32_bf16(v0, bpB.f, oB0, 0, 0, 0);
                oB1 = __builtin_amdgcn_mfma_f32_16x16x32_bf16(v1, bpB.f, oB1, 0, 0, 0);
                oB2 = __builtin_amdgcn_mfma_f32_16x16x32_bf16(v2, bpB.f, oB2, 0, 0, 0);
                oB3 = __builtin_amdgcn_mfma_f32_16x16x32_bf16(v3, bpB.f, oB3, 0, 0, 0);
            }
        }

        lA += __shfl_xor(lA, 16); lA += __shfl_xor(lA, 32);
        lB += __shfl_xor(lB, 16); lB += __shfl_xor(lB, 32);

        // ---- partial stores (bf16; always, eighths with n==0 write zeros) ----
        __bf16* ob = opart + ((long)qr * NB + batch) * (long)(SD * DH) + (long)myq * DH;
        {
            floatx4 ovA[4] = {oA0, oA1, oA2, oA3};
            floatx4 ovB[4] = {oB0, oB1, oB2, oB3};
#pragma unroll
            for (int dt = 0; dt < 4; ++dt) {
                uint2 sA, sB;
                sA.x = pack_bf16_2(ovA[dt][0], ovA[dt][1]);
                sA.y = pack_bf16_2(ovA[dt][2], ovA[dt][3]);
                sB.x = pack_bf16_2(ovB[dt][0], ovB[dt][1]);
                sB.y = pack_bf16_2(ovB[dt][2], ovB[dt][3]);
                *(uint2*)(ob + (c)      * DH + dt*16 + quad*4) = sA;
                *(uint2*)(ob + (16 + c) * DH + dt*16 + quad*4) = sB;
            }
        }
        if (quad == 0) {
            lpart[((long)qr * NB + batch) * SD + myq + c]      = lA;
            lpart[((long)qr * NB + batch) * SD + myq + 16 + c] = lB;
        }
    }
}

// out = (sum of 8 key-eighth bf16 O partials) / (sum of 8 l partials)
// one thread = 4 consecutive d elements (vectorized)
__global__ __launch_bounds__(256) void combine_kernel(const __bf16* __restrict__ opart,
                                                      const float* __restrict__ lpart,
                                                      float* __restrict__ out) {
    const long t    = (long)blockIdx.x * 256 + threadIdx.x;  // 0..262143
    const long base = t * 4;                                 // element index
    const long qq   = base >> 6;                             // b*SD + q
    float n0 = 0.f, n1 = 0.f, n2 = 0.f, n3 = 0.f, den = 0.f;
#pragma unroll
    for (int qr = 0; qr < 8; ++qr) {
        bf16x4 p = *(const bf16x4*)(opart + ((long)qr << 20) + base);
        n0 += (float)p[0]; n1 += (float)p[1]; n2 += (float)p[2]; n3 += (float)p[3];
        den += lpart[((long)qr << 14) + qq];
    }
    float inv = 1.0f / den;
    float4 o; o.x = n0 * inv; o.y = n1 * inv; o.z = n2 * inv; o.w = n3 * inv;
    *(float4*)(out + base) = o;
}

extern "C" void kernel_launch(void* const* d_in, const int* in_sizes, int n_in,
                              void* d_out, int out_size, void* d_ws, size_t ws_size,
                              hipStream_t stream) {
    const float* q = (const float*)d_in[0];
    const float* k = (const float*)d_in[1];
    const float* v = (const float*)d_in[2];
    float* out = (float*)d_out;
    __bf16* vtb   = (__bf16*)d_ws;                                 // 2MB
    __bf16* opart = (__bf16*)((char*)d_ws + (4u << 20));           // 16MB
    float*  lpart = (float*)((char*)d_ws + (20u << 20));           // 512KB
    prep_kernel<<<dim3(1024), dim3(256), 0, stream>>>(v, vtb);
    fa_kernel<<<dim3(512), dim3(256), 0, stream>>>(q, k, vtb, opart, lpart);
    combine_kernel<<<dim3(1024), dim3(256), 0, stream>>>(opart, lpart, out);
}